// Round 11
// baseline (385.563 us; speedup 1.0000x reference)
//
#include <hip/hip_runtime.h>
#include <hip/hip_bf16.h>

#define NODES 11520
#define EDGES 184320
#define NB    64      // batch
#define NPG   180
#define CAP   64      // max in-degree bucket capacity (true max ~40)

typedef __bf16 bf16x8 __attribute__((ext_vector_type(8)));
typedef __bf16 bf16x4 __attribute__((ext_vector_type(4)));
typedef float  f32x4  __attribute__((ext_vector_type(4)));

// ---------------------------------------------------------------------------
// Fused prep: one dispatch for 4 independent roles (cuts 3 launch gaps).
//  blocks [0,2048):    transpose W2/W3 -> bf16 [N,K]
//  blocks [2048,2912): transpose Wp/Ws/Wt -> WHt + biascat
//  blocks [2912,3632): edge histogram + bucket scatter
//  blocks [3632,3696): k_init (zc + Y1)
__global__ __launch_bounds__(256) void k_prep(
    const float* __restrict__ W2, const float* __restrict__ W3,
    __bf16* __restrict__ W2t, __bf16* __restrict__ W3t,
    const float* __restrict__ Wp, const float* __restrict__ Ws,
    const float* __restrict__ Wt, __bf16* __restrict__ WHt,
    const float* __restrict__ bp, const float* __restrict__ bs,
    const float* __restrict__ bt, float* __restrict__ bc,
    const int* __restrict__ ei, int* __restrict__ counts,
    int* __restrict__ bucket,
    const float* __restrict__ z, const float* __restrict__ cond,
    const float* __restrict__ Wi, const float* __restrict__ bi,
    const float* __restrict__ W1, float* __restrict__ Y1)
{
    __shared__ union {
        float tr[32][33];
        struct { float xr[384]; float part[4][256]; float zr[256]; } init;
    } sm;
    const int b = blockIdx.x, t = threadIdx.x;

    if (b < 2048) {               // ---- transW ----
        const float* W = (b >= 1024) ? W3 : W2;
        __bf16* WT = (b >= 1024) ? W3t : W2t;
        const int rem = b & 1023;
        const int n0 = (rem & 31) * 32, k0 = (rem >> 5) * 32;
        const int tx = t & 31, ty = t >> 5;
#pragma unroll
        for (int i = 0; i < 32; i += 8)
            sm.tr[ty + i][tx] = W[(size_t)(k0 + ty + i) * 1024 + n0 + tx];
        __syncthreads();
#pragma unroll
        for (int i = 0; i < 32; i += 8)
            WT[(size_t)(n0 + ty + i) * 1024 + k0 + tx] = (__bf16)sm.tr[tx][ty + i];
        return;
    }
    if (b < 2912) {               // ---- transH + biascat ----
        const int idx = b - 2048;           // 0..863  (9 x 32 x 3)
        const int zz = idx / 288, r2 = idx % 288;
        const int x = r2 % 9, y = r2 / 9;
        if (x == 8) {
            if (y == 0) {
                const float v = zz == 0 ? bp[t] : zz == 1 ? bs[t] : bt[t];
                bc[zz * 256 + t] = v;
            }
            return;
        }
        const float* W = zz == 0 ? Wp : zz == 1 ? Ws : Wt;
        __bf16* WT = WHt + (size_t)zz * 256 * 1024;
        const int n0 = x * 32, k0 = y * 32;
        const int tx = t & 31, ty = t >> 5;
#pragma unroll
        for (int i = 0; i < 32; i += 8)
            sm.tr[ty + i][tx] = W[(size_t)(k0 + ty + i) * 256 + n0 + tx];
        __syncthreads();
#pragma unroll
        for (int i = 0; i < 32; i += 8)
            WT[(size_t)(n0 + ty + i) * 1024 + k0 + tx] = (__bf16)sm.tr[tx][ty + i];
        return;
    }
    if (b < 3632) {               // ---- hist ----
        const int e = (b - 2912) * 256 + t;  // EDGES = 720*256 exactly
        const int s = ei[e], d = ei[EDGES + e];
        const int pos = atomicAdd(&counts[d], 1);
        if (pos < CAP) bucket[(size_t)d * CAP + pos] = s;
        return;
    }
    {                             // ---- k_init ----
        const int bb = b - 3632;
        sm.init.xr[t] = (t < 256) ? z[bb * 256 + t] : 0.f;
        if (t < 128) sm.init.xr[256 + t] = cond[bb * 128 + t];
        __syncthreads();
        {
            const int kq = t >> 6, tc = t & 63;
            f32x4 acc = {0.f, 0.f, 0.f, 0.f};
            const float* wbase = Wi + (size_t)(kq * 96) * 256 + 4 * tc;
            const float* xb = sm.init.xr + kq * 96;
#pragma unroll 8
            for (int k = 0; k < 96; ++k) {
                const float4 w = *(const float4*)(wbase + (size_t)k * 256);
                const float x = xb[k];
                acc[0] = fmaf(x, w.x, acc[0]);
                acc[1] = fmaf(x, w.y, acc[1]);
                acc[2] = fmaf(x, w.z, acc[2]);
                acc[3] = fmaf(x, w.w, acc[3]);
            }
            *(f32x4*)&sm.init.part[kq][4 * tc] = acc;
        }
        __syncthreads();
        sm.init.zr[t] = fmaxf(bi[t] + sm.init.part[0][t] + sm.init.part[1][t] +
                              sm.init.part[2][t] + sm.init.part[3][t], 0.f);
        __syncthreads();
        {
            f32x4 acc = {0.f, 0.f, 0.f, 0.f};
#pragma unroll 8
            for (int k = 0; k < 256; ++k) {
                const float4 w = *(const float4*)(W1 + (size_t)k * 1024 + 4 * t);
                const float x = sm.init.zr[k];
                acc[0] = fmaf(x, w.x, acc[0]);
                acc[1] = fmaf(x, w.y, acc[1]);
                acc[2] = fmaf(x, w.z, acc[2]);
                acc[3] = fmaf(x, w.w, acc[3]);
            }
            *(f32x4*)(Y1 + (size_t)bb * 1024 + 4 * t) = acc;
        }
    }
}

// ---------------------------------------------------------------------------
// h1[n,:] = Y1[n/180,:] + W1[256 + n%180,:] (stored bf16); scores from fp32.
// Also zeros the OTHER score buffer (consumed by layer-2 gemm atomics).
__global__ __launch_bounds__(256) void k_h1(
    const float* __restrict__ Y1, const float* __restrict__ W1,
    const float* __restrict__ atts, const float* __restrict__ attd,
    __bf16* __restrict__ hb, float* __restrict__ asb, float* __restrict__ adb,
    float* __restrict__ zas, float* __restrict__ zad)
{
    const int n = blockIdx.x, t = threadIdx.x;
    if (t < 4)      zas[n * 4 + t] = 0.f;
    else if (t < 8) zad[n * 4 + (t - 4)] = 0.f;
    const int g = n / NPG, o = n - g * NPG;
    const float4 y = *(const float4*)(Y1 + (size_t)g * 1024 + 4 * t);
    const float4 w = *(const float4*)(W1 + (size_t)(256 + o) * 1024 + 4 * t);
    const float4 h = {y.x + w.x, y.y + w.y, y.z + w.z, y.w + w.w};
    bf16x4 hv = {(__bf16)h.x, (__bf16)h.y, (__bf16)h.z, (__bf16)h.w};
    *(bf16x4*)(hb + (size_t)n * 1024 + 4 * t) = hv;
    const int head = t >> 6, c0 = (t & 63) * 4;
    const float4 s4 = *(const float4*)(atts + head * 256 + c0);
    const float4 d4 = *(const float4*)(attd + head * 256 + c0);
    float ps = h.x * s4.x + h.y * s4.y + h.z * s4.z + h.w * s4.w;
    float pd = h.x * d4.x + h.y * d4.y + h.z * d4.z + h.w * d4.w;
    for (int off = 32; off; off >>= 1) {
        ps += __shfl_xor(ps, off, 64);
        pd += __shfl_xor(pd, off, 64);
    }
    if ((t & 63) == 0) { asb[n * 4 + head] = ps; adb[n * 4 + head] = pd; }
}

// ---------------------------------------------------------------------------
// GAT aggregation: 2 dst nodes per block (128 threads each), bf16x8 loads,
// unroll-8 gather (8 independent 16B loads in flight). XCD-contiguous ranges.
__global__ __launch_bounds__(256) void k_agg(
    const __bf16* __restrict__ hb, const float* __restrict__ asb,
    const float* __restrict__ adb, const int* __restrict__ counts,
    const int* __restrict__ bucket, const float* __restrict__ bias,
    __bf16* __restrict__ xout, float* __restrict__ zas, float* __restrict__ zad)
{
    const int b = blockIdx.x;                // 5760 blocks
    const int nb = (b & 7) * (NODES / 8) + 2 * (b >> 3);
    const int t = threadIdx.x;
    const int half = t >> 7, tt = t & 127;
    const int n = nb + half;
    __shared__ float sc[2][CAP + 1][4];
    __shared__ int   ssrc[2][CAP + 1];
    __shared__ float sinv[2][4];
    if (zas != nullptr) {
        if (t < 8)       zas[nb * 4 + t] = 0.f;
        else if (t < 16) zad[nb * 4 + (t - 8)] = 0.f;
    }
    const int deg = min(counts[n], CAP);
    const int ne  = deg + 1;                  // + self loop
    if (tt < deg)       ssrc[half][tt] = bucket[(size_t)n * CAP + tt];
    else if (tt == deg) ssrc[half][tt] = n;
    __syncthreads();
    if (tt < ne) {
        const int s = ssrc[half][tt];
        const float4 as4 = *(const float4*)(asb + (size_t)s * 4);
        const float4 ad4 = *(const float4*)(adb + (size_t)n * 4);
        const float v0 = as4.x + ad4.x, v1 = as4.y + ad4.y;
        const float v2 = as4.z + ad4.z, v3 = as4.w + ad4.w;
        sc[half][tt][0] = v0 > 0.f ? v0 : 0.2f * v0;
        sc[half][tt][1] = v1 > 0.f ? v1 : 0.2f * v1;
        sc[half][tt][2] = v2 > 0.f ? v2 : 0.2f * v2;
        sc[half][tt][3] = v3 > 0.f ? v3 : 0.2f * v3;
    }
    __syncthreads();
    const int ln = t & 63, hw = (t >> 6) & 1;
#pragma unroll
    for (int hh = 0; hh < 2; ++hh) {          // each wave: 2 heads of its node
        const int head = hw * 2 + hh;
        float m = -1e30f;
        for (int k = ln; k < ne; k += 64) m = fmaxf(m, sc[half][k][head]);
        for (int off = 32; off; off >>= 1) m = fmaxf(m, __shfl_xor(m, off, 64));
        float s = 0.f;
        for (int k = ln; k < ne; k += 64) {
            const float p = __expf(sc[half][k][head] - m);
            sc[half][k][head] = p;
            s += p;
        }
        for (int off = 32; off; off >>= 1) s += __shfl_xor(s, off, 64);
        if (ln == 0) sinv[half][head] = 1.f / (s + 1e-16f);
    }
    __syncthreads();
    const int j0 = tt * 8, hd = tt >> 5;
    const float inv = sinv[half][hd];
    float a[8] = {0, 0, 0, 0, 0, 0, 0, 0};
    int k = 0;
    for (; k + 8 <= ne; k += 8) {            // 8 independent 16B loads in flight
        float al[8]; bf16x8 hv[8];
#pragma unroll
        for (int u = 0; u < 8; ++u) {
            al[u] = sc[half][k + u][hd] * inv;
            hv[u] = *(const bf16x8*)(hb + (size_t)ssrc[half][k + u] * 1024 + j0);
        }
#pragma unroll
        for (int u = 0; u < 8; ++u)
#pragma unroll
            for (int e = 0; e < 8; ++e)
                a[e] = fmaf(al[u], (float)hv[u][e], a[e]);
    }
    for (; k < ne; ++k) {
        const float al = sc[half][k][hd] * inv;
        const bf16x8 hv = *(const bf16x8*)(hb + (size_t)ssrc[half][k] * 1024 + j0);
#pragma unroll
        for (int e = 0; e < 8; ++e)
            a[e] = fmaf(al, (float)hv[e], a[e]);
    }
    const float4 b4a = *(const float4*)(bias + j0);
    const float4 b4b = *(const float4*)(bias + j0 + 4);
    bf16x8 o;
    o[0] = (__bf16)fmaxf(a[0] + b4a.x, 0.f);
    o[1] = (__bf16)fmaxf(a[1] + b4a.y, 0.f);
    o[2] = (__bf16)fmaxf(a[2] + b4a.z, 0.f);
    o[3] = (__bf16)fmaxf(a[3] + b4a.w, 0.f);
    o[4] = (__bf16)fmaxf(a[4] + b4b.x, 0.f);
    o[5] = (__bf16)fmaxf(a[5] + b4b.y, 0.f);
    o[6] = (__bf16)fmaxf(a[6] + b4b.z, 0.f);
    o[7] = (__bf16)fmaxf(a[7] + b4b.w, 0.f);
    *(bf16x8*)(xout + (size_t)n * 1024 + j0) = o;
}

// ---------------------------------------------------------------------------
// R9-proven GEMM machinery: 128x128 tile, BK=64, SINGLE 32KB LDS buffer.
// (dbuf, LDS-free, 64-tile all measured neutral-or-worse: R7/R8/R10.)
#define STAGE(kbase)                                                           \
    {                                                                          \
        _Pragma("unroll")                                                      \
        for (int h = 0; h < 2; ++h) {                                          \
            _Pragma("unroll")                                                  \
            for (int cc = 0; cc < 2; ++cc) {                                   \
                const int c = 2 * w + cc;                                      \
                const int row = c * 16 + lr;                                   \
                __builtin_amdgcn_global_load_lds(                              \
                    (const __attribute__((address_space(1))) void*)            \
                        (A + (size_t)(m0 + row) * K + (kbase) + h * 32 + lk),  \
                    (__attribute__((address_space(3))) void*)                  \
                        (As + h * 4096 + c * 512), 16, 0, 0);                  \
                __builtin_amdgcn_global_load_lds(                              \
                    (const __attribute__((address_space(1))) void*)            \
                        (BT + (size_t)(n0 + row) * K + (kbase) + h * 32 + lk), \
                    (__attribute__((address_space(3))) void*)                  \
                        (Bs + h * 4096 + c * 512), 16, 0, 0);                  \
            }                                                                  \
        }                                                                      \
    }

#define GEMM_MAINLOOP()                                                        \
    f32x4 acc[4][4];                                                           \
    _Pragma("unroll")                                                          \
    for (int i = 0; i < 4; ++i)                                                \
        _Pragma("unroll")                                                      \
        for (int j = 0; j < 4; ++j)                                            \
            acc[i][j] = (f32x4){0.f, 0.f, 0.f, 0.f};                           \
    for (int k0 = 0; k0 < K; k0 += 64) {                                       \
        STAGE(k0);                                                             \
        __syncthreads();                                                       \
        _Pragma("unroll")                                                      \
        for (int h = 0; h < 2; ++h) {                                          \
            bf16x8 af[4], bfr[4];                                              \
            _Pragma("unroll")                                                  \
            for (int i = 0; i < 4; ++i)                                        \
                af[i] = *(const bf16x8*)(As + h * 4096 +                       \
                                         (wm + i * 16 + r16) * 32 + quad * 8); \
            _Pragma("unroll")                                                  \
            for (int j = 0; j < 4; ++j)                                        \
                bfr[j] = *(const bf16x8*)(Bs + h * 4096 +                      \
                                          (wn + j * 16 + r16) * 32 + quad * 8);\
            _Pragma("unroll")                                                  \
            for (int i = 0; i < 4; ++i)                                        \
                _Pragma("unroll")                                              \
                for (int j = 0; j < 4; ++j)                                    \
                    acc[i][j] = __builtin_amdgcn_mfma_f32_16x16x32_bf16(       \
                        af[i], bfr[j], acc[i][j], 0, 0, 0);                    \
        }                                                                      \
        __syncthreads();                                                       \
    }

// ---------------------------------------------------------------------------
// bf16 MFMA GEMM, h-producing variant: Cb(bf16) = A @ BT^T + fused per-row
// attention dots (fp32 accs, atomics into zeroed asb/adb). N must be 1024.
__global__ __launch_bounds__(256) void gemm_bf16_h(
    const __bf16* __restrict__ A, const __bf16* __restrict__ BT,
    __bf16* __restrict__ Cb,
    const float* __restrict__ atts, const float* __restrict__ attd,
    float* __restrict__ asb, float* __restrict__ adb,
    int M, int N, int K)
{
    const int lb = blockIdx.x;
    const int g = lb & 7, idx = lb >> 3;
    const int bx = idx & 7;                  // nx = 8
    const int by = (idx >> 3) * 8 + g;
    if (by * 128 >= M) return;
    const int m0 = by * 128, n0 = bx * 128;

    __shared__ __bf16 As[2 * 128 * 32];      // 16KB: two 32-k sub-tiles
    __shared__ __bf16 Bs[2 * 128 * 32];      // 16KB
    const int tid = threadIdx.x;
    const int w = tid >> 6, l = tid & 63;
    const int lr = l >> 2, lk = (l & 3) * 8;
    const int quad = l >> 4, r16 = l & 15;
    const int wm = (w >> 1) * 64, wn = (w & 1) * 64;

    GEMM_MAINLOOP();

    // Epilogue: bf16 store + fused attention dots. Hoisted Sa/Da (4 cols/thr).
    const int head = (n0 + wn) >> 8;
    float sa[4], da[4];
#pragma unroll
    for (int j = 0; j < 4; ++j) {
        const int cl = (n0 + wn + j * 16 + r16) & 255;
        sa[j] = atts[head * 256 + cl];
        da[j] = attd[head * 256 + cl];
    }
#pragma unroll
    for (int i = 0; i < 4; ++i) {
#pragma unroll
        for (int r = 0; r < 4; ++r) {
            const int mg = m0 + wm + i * 16 + quad * 4 + r;
            float ps = 0.f, pd = 0.f;
#pragma unroll
            for (int j = 0; j < 4; ++j) {
                const int ng = n0 + wn + j * 16 + r16;
                const float v = acc[i][j][r];
                ps = fmaf(v, sa[j], ps);
                pd = fmaf(v, da[j], pd);
                Cb[(size_t)mg * N + ng] = (__bf16)v;
            }
            for (int off = 8; off; off >>= 1) {
                ps += __shfl_xor(ps, off, 64);
                pd += __shfl_xor(pd, off, 64);
            }
            if (r16 == 0) {
                atomicAdd(&asb[mg * 4 + head], ps);
                atomicAdd(&adb[mg * 4 + head], pd);
            }
        }
    }
}

// ---------------------------------------------------------------------------
// Heads GEMM with fully fused output: relu(acc + biascat) dotted with the
// small head matrices, atomicAdd into zeroed out[]. No T materialization.
__global__ __launch_bounds__(256) void gemm_heads(
    const __bf16* __restrict__ A, const __bf16* __restrict__ BT,
    const float* __restrict__ biascat,
    const float* __restrict__ Wfp, const float* __restrict__ bfp,
    const float* __restrict__ Wfs, const float* __restrict__ bfs,
    const float* __restrict__ Wft, const float* __restrict__ bft,
    float* __restrict__ out, int M, int K)
{
    const int lb = blockIdx.x;
    const int g = lb & 7, idx = lb >> 3;
    const int bx = idx % 6;                  // nx = 6 (N = 768)
    const int by = (idx / 6) * 8 + g;
    if (by * 128 >= M) return;
    const int m0 = by * 128, n0 = bx * 128;

    __shared__ __bf16 As[2 * 128 * 32];
    __shared__ __bf16 Bs[2 * 128 * 32];
    const int tid = threadIdx.x;
    const int w = tid >> 6, l = tid & 63;
    const int lr = l >> 2, lk = (l & 3) * 8;
    const int quad = l >> 4, r16 = l & 15;
    const int wm = (w >> 1) * 64, wn = (w & 1) * 64;

    GEMM_MAINLOOP();

    // Epilogue: per-row partial dots with head weights -> atomics.
    const int hg = bx >> 1;                  // 0 pos, 1 size, 2 theta
    const float* Wf = hg == 0 ? Wfp : hg == 1 ? Wfs : Wft;
    const int nout = hg == 2 ? 1 : 2;
    float wf0[4], wf1[4], bz[4];
#pragma unroll
    for (int j = 0; j < 4; ++j) {
        const int ng = n0 + wn + j * 16 + r16;
        const int cl = ng & 255;
        bz[j]  = biascat[ng];
        wf0[j] = Wf[cl * nout];
        wf1[j] = nout == 2 ? Wf[cl * nout + 1] : 0.f;
    }
    // final bias exactly once per row: even column-block, wn==0 wave only
    const bool addb = ((bx & 1) == 0) && (wn == 0);
    const float fb0 = hg == 0 ? bfp[0] : hg == 1 ? bfs[0] : bft[0];
    const float fb1 = hg == 2 ? 0.f : (hg == 0 ? bfp[1] : bfs[1]);
#pragma unroll
    for (int i = 0; i < 4; ++i) {
#pragma unroll
        for (int r = 0; r < 4; ++r) {
            const int mg = m0 + wm + i * 16 + quad * 4 + r;
            float o0 = 0.f, o1 = 0.f;
#pragma unroll
            for (int j = 0; j < 4; ++j) {
                const float v = fmaxf(acc[i][j][r] + bz[j], 0.f);
                o0 = fmaf(v, wf0[j], o0);
                o1 = fmaf(v, wf1[j], o1);
            }
            for (int off = 8; off; off >>= 1) {
                o0 += __shfl_xor(o0, off, 64);
                o1 += __shfl_xor(o1, off, 64);
            }
            if (r16 == 0) {
                if (addb) { o0 += fb0; o1 += fb1; }
                const size_t base = hg == 0 ? 2 * (size_t)mg
                                 : hg == 1 ? 2 * (size_t)NODES + 2 * (size_t)mg
                                 : 4 * (size_t)NODES + (size_t)mg;
                atomicAdd(&out[base], o0);
                if (nout == 2) atomicAdd(&out[base + 1], o1);
            }
        }
    }
}

// ---------------------------------------------------------------------------
extern "C" void kernel_launch(void* const* d_in, const int* in_sizes, int n_in,
                              void* d_out, int out_size, void* d_ws, size_t ws_size,
                              hipStream_t stream)
{
    const float* z    = (const float*)d_in[0];
    const float* cond = (const float*)d_in[1];
    const int*   ei   = (const int*)  d_in[2];
    const float* Wi   = (const float*)d_in[4];
    const float* bi   = (const float*)d_in[5];
    const float* W1   = (const float*)d_in[6];
    const float* as1  = (const float*)d_in[7];
    const float* ad1  = (const float*)d_in[8];
    const float* b1   = (const float*)d_in[9];
    const float* W2   = (const float*)d_in[10];
    const float* as2  = (const float*)d_in[11];
    const float* ad2  = (const float*)d_in[12];
    const float* b2   = (const float*)d_in[13];
    const float* W3   = (const float*)d_in[14];
    const float* as3  = (const float*)d_in[15];
    const float* ad3  = (const float*)d_in[16];
    const float* b3   = (const float*)d_in[17];
    const float* Wp   = (const float*)d_in[18];
    const float* bp   = (const float*)d_in[19];
    const float* Wfp  = (const float*)d_in[20];
    const float* bfp  = (const float*)d_in[21];
    const float* Ws   = (const float*)d_in[22];
    const float* bs   = (const float*)d_in[23];
    const float* Wfs  = (const float*)d_in[24];
    const float* bfs  = (const float*)d_in[25];
    const float* Wt   = (const float*)d_in[26];
    const float* bt   = (const float*)d_in[27];
    const float* Wft  = (const float*)d_in[28];
    const float* bft  = (const float*)d_in[29];
    float* out = (float*)d_out;

    // ---- workspace carve (bytes) ----
    char* p = (char*)d_ws;
    __bf16* hb    = (__bf16*)p;           p += (size_t)NODES * 1024 * 2;  // 23.6 MB
    __bf16* xb16  = (__bf16*)p;           p += (size_t)NODES * 1024 * 2;  // 23.6 MB
    float* asA    = (float*)p;            p += (size_t)NODES * 4 * 4;
    float* adA    = (float*)p;            p += (size_t)NODES * 4 * 4;
    float* asB    = (float*)p;            p += (size_t)NODES * 4 * 4;
    float* adB    = (float*)p;            p += (size_t)NODES * 4 * 4;
    float* Y1     = (float*)p;            p += 64 * 1024 * 4;
    int*   counts = (int*)p;              p += (size_t)NODES * 4;
    int*   bucket = (int*)p;              p += (size_t)NODES * CAP * 4;   // 2.95 MB
    __bf16* W2t   = (__bf16*)p;           p += (size_t)1024 * 1024 * 2;   // 2 MB
    __bf16* W3t   = (__bf16*)p;           p += (size_t)1024 * 1024 * 2;   // 2 MB
    __bf16* WHt   = (__bf16*)p;           p += (size_t)768 * 1024 * 2;    // 1.5 MB
    float* biascat= (float*)p;            p += 768 * 4;

    hipMemsetAsync(out, 0, (size_t)out_size * sizeof(float), stream);
    hipMemsetAsync(counts, 0, NODES * sizeof(int), stream);

    // ---- fused prep: transW + transH + hist + k_init in ONE dispatch ----
    k_prep<<<3696, 256, 0, stream>>>(W2, W3, W2t, W3t,
                                     Wp, Ws, Wt, WHt, bp, bs, bt, biascat,
                                     ei, counts, bucket,
                                     z, cond, Wi, bi, W1, Y1);

    // ---- layer 1 (GEMM collapsed: one-hot + batch-broadcast structure) ----
    k_h1<<<NODES, 256, 0, stream>>>(Y1, W1, as1, ad1, hb, asA, adA, asB, adB);
    k_agg<<<NODES / 2, 256, 0, stream>>>(hb, asA, adA, counts, bucket, b1,
                                         xb16, nullptr, nullptr);

    // ---- layer 2 (scores fused into GEMM epilogue -> asB/adB) ----
    gemm_bf16_h<<<8 * 96, 256, 0, stream>>>(xb16, W2t, hb, as2, ad2,
                                            asB, adB, NODES, 1024, 1024);
    k_agg<<<NODES / 2, 256, 0, stream>>>(hb, asB, adB, counts, bucket, b2,
                                         xb16, asA, adA);   // zeroes A bufs
    // ---- layer 3 (scores -> asA/adA, zeroed above) ----
    gemm_bf16_h<<<8 * 96, 256, 0, stream>>>(xb16, W3t, hb, as3, ad3,
                                            asA, adA, NODES, 1024, 1024);
    k_agg<<<NODES / 2, 256, 0, stream>>>(hb, asA, adA, counts, bucket, b3,
                                         xb16, nullptr, nullptr);

    // ---- fused heads: dots folded into GEMM epilogue, atomics into out ----
    gemm_heads<<<6 * 96, 256, 0, stream>>>(xb16, WHt, biascat,
                                           Wfp, bfp, Wfs, bfs, Wft, bft,
                                           out, NODES, 1024);
}

// Round 12
// 377.484 us; speedup vs baseline: 1.0214x; 1.0214x over previous
//
#include <hip/hip_runtime.h>
#include <hip/hip_bf16.h>

#define NODES 11520
#define EDGES 184320
#define NB    64      // batch
#define NPG   180
#define CAP   64      // max in-degree bucket capacity (true max ~40)

typedef __bf16 bf16x8 __attribute__((ext_vector_type(8)));
typedef __bf16 bf16x4 __attribute__((ext_vector_type(4)));
typedef float  f32x4  __attribute__((ext_vector_type(4)));

// ---------------------------------------------------------------------------
// Fused: zc = relu(concat(z,cond) @ W_init + b_init); Y1 = zc @ W1[0:256,:]
__global__ __launch_bounds__(256) void k_init(
    const float* __restrict__ z, const float* __restrict__ cond,
    const float* __restrict__ Wi, const float* __restrict__ bi,
    const float* __restrict__ W1, float* __restrict__ Y1)
{
    __shared__ float xr[384];
    __shared__ float part[4][256];
    __shared__ float zr[256];
    const int b = blockIdx.x, t = threadIdx.x;
    xr[t] = (t < 256) ? z[b * 256 + t] : 0.f;
    if (t < 128) xr[256 + t] = cond[b * 128 + t];
    __syncthreads();
    {
        const int kq = t >> 6, tc = t & 63;
        f32x4 acc = {0.f, 0.f, 0.f, 0.f};
        const float* wbase = Wi + (size_t)(kq * 96) * 256 + 4 * tc;
        const float* xb = xr + kq * 96;
#pragma unroll 8
        for (int k = 0; k < 96; ++k) {
            const float4 w = *(const float4*)(wbase + (size_t)k * 256);
            const float x = xb[k];
            acc[0] = fmaf(x, w.x, acc[0]);
            acc[1] = fmaf(x, w.y, acc[1]);
            acc[2] = fmaf(x, w.z, acc[2]);
            acc[3] = fmaf(x, w.w, acc[3]);
        }
        *(f32x4*)&part[kq][4 * tc] = acc;
    }
    __syncthreads();
    zr[t] = fmaxf(bi[t] + part[0][t] + part[1][t] + part[2][t] + part[3][t], 0.f);
    __syncthreads();
    {
        f32x4 acc = {0.f, 0.f, 0.f, 0.f};
#pragma unroll 8
        for (int k = 0; k < 256; ++k) {
            const float4 w = *(const float4*)(W1 + (size_t)k * 1024 + 4 * t);
            const float x = zr[k];
            acc[0] = fmaf(x, w.x, acc[0]);
            acc[1] = fmaf(x, w.y, acc[1]);
            acc[2] = fmaf(x, w.z, acc[2]);
            acc[3] = fmaf(x, w.w, acc[3]);
        }
        *(f32x4*)(Y1 + (size_t)b * 1024 + 4 * t) = acc;
    }
}

// ---------------------------------------------------------------------------
// h1[n,:] = Y1[n/180,:] + W1[256 + n%180,:] (stored bf16); scores from fp32.
// Also zeros the OTHER score buffer (consumed by layer-2 gemm atomics).
__global__ __launch_bounds__(256) void k_h1(
    const float* __restrict__ Y1, const float* __restrict__ W1,
    const float* __restrict__ atts, const float* __restrict__ attd,
    __bf16* __restrict__ hb, float* __restrict__ asb, float* __restrict__ adb,
    float* __restrict__ zas, float* __restrict__ zad)
{
    const int n = blockIdx.x, t = threadIdx.x;
    if (t < 4)      zas[n * 4 + t] = 0.f;
    else if (t < 8) zad[n * 4 + (t - 4)] = 0.f;
    const int g = n / NPG, o = n - g * NPG;
    const float4 y = *(const float4*)(Y1 + (size_t)g * 1024 + 4 * t);
    const float4 w = *(const float4*)(W1 + (size_t)(256 + o) * 1024 + 4 * t);
    const float4 h = {y.x + w.x, y.y + w.y, y.z + w.z, y.w + w.w};
    bf16x4 hv = {(__bf16)h.x, (__bf16)h.y, (__bf16)h.z, (__bf16)h.w};
    *(bf16x4*)(hb + (size_t)n * 1024 + 4 * t) = hv;
    const int head = t >> 6, c0 = (t & 63) * 4;
    const float4 s4 = *(const float4*)(atts + head * 256 + c0);
    const float4 d4 = *(const float4*)(attd + head * 256 + c0);
    float ps = h.x * s4.x + h.y * s4.y + h.z * s4.z + h.w * s4.w;
    float pd = h.x * d4.x + h.y * d4.y + h.z * d4.z + h.w * d4.w;
    for (int off = 32; off; off >>= 1) {
        ps += __shfl_xor(ps, off, 64);
        pd += __shfl_xor(pd, off, 64);
    }
    if ((t & 63) == 0) { asb[n * 4 + head] = ps; adb[n * 4 + head] = pd; }
}

// ---------------------------------------------------------------------------
// Bucket-CSR build: histogram + direct scatter (cap 64)
__global__ __launch_bounds__(256) void k_hist(
    const int* __restrict__ ei, int* __restrict__ counts,
    int* __restrict__ bucket)
{
    const int e = blockIdx.x * 256 + threadIdx.x;
    if (e >= EDGES) return;
    const int s = ei[e], d = ei[EDGES + e];
    const int pos = atomicAdd(&counts[d], 1);
    if (pos < CAP) bucket[(size_t)d * CAP + pos] = s;
}

// ---------------------------------------------------------------------------
// GAT aggregation: 2 dst nodes per block (128 threads each), bf16x8 loads.
// XCD-contiguous node ranges; optional zeroing of the other score buffer.
__global__ __launch_bounds__(256) void k_agg(
    const __bf16* __restrict__ hb, const float* __restrict__ asb,
    const float* __restrict__ adb, const int* __restrict__ counts,
    const int* __restrict__ bucket, const float* __restrict__ bias,
    __bf16* __restrict__ xout, float* __restrict__ zas, float* __restrict__ zad)
{
    const int b = blockIdx.x;                // 5760 blocks
    const int nb = (b & 7) * (NODES / 8) + 2 * (b >> 3);
    const int t = threadIdx.x;
    const int half = t >> 7, tt = t & 127;
    const int n = nb + half;
    __shared__ float sc[2][CAP + 1][4];
    __shared__ int   ssrc[2][CAP + 1];
    __shared__ float sinv[2][4];
    if (zas != nullptr) {
        if (t < 8)       zas[nb * 4 + t] = 0.f;
        else if (t < 16) zad[nb * 4 + (t - 8)] = 0.f;
    }
    const int deg = min(counts[n], CAP);
    const int ne  = deg + 1;                  // + self loop
    if (tt < deg)       ssrc[half][tt] = bucket[(size_t)n * CAP + tt];
    else if (tt == deg) ssrc[half][tt] = n;
    __syncthreads();
    if (tt < ne) {
        const int s = ssrc[half][tt];
        const float4 as4 = *(const float4*)(asb + (size_t)s * 4);
        const float4 ad4 = *(const float4*)(adb + (size_t)n * 4);
        const float v0 = as4.x + ad4.x, v1 = as4.y + ad4.y;
        const float v2 = as4.z + ad4.z, v3 = as4.w + ad4.w;
        sc[half][tt][0] = v0 > 0.f ? v0 : 0.2f * v0;
        sc[half][tt][1] = v1 > 0.f ? v1 : 0.2f * v1;
        sc[half][tt][2] = v2 > 0.f ? v2 : 0.2f * v2;
        sc[half][tt][3] = v3 > 0.f ? v3 : 0.2f * v3;
    }
    __syncthreads();
    const int ln = t & 63, hw = (t >> 6) & 1;
#pragma unroll
    for (int hh = 0; hh < 2; ++hh) {          // each wave: 2 heads of its node
        const int head = hw * 2 + hh;
        float m = -1e30f;
        for (int k = ln; k < ne; k += 64) m = fmaxf(m, sc[half][k][head]);
        for (int off = 32; off; off >>= 1) m = fmaxf(m, __shfl_xor(m, off, 64));
        float s = 0.f;
        for (int k = ln; k < ne; k += 64) {
            const float p = __expf(sc[half][k][head] - m);
            sc[half][k][head] = p;
            s += p;
        }
        for (int off = 32; off; off >>= 1) s += __shfl_xor(s, off, 64);
        if (ln == 0) sinv[half][head] = 1.f / (s + 1e-16f);
    }
    __syncthreads();
    const int j0 = tt * 8, hd = tt >> 5;
    const float inv = sinv[half][hd];
    float a[8] = {0, 0, 0, 0, 0, 0, 0, 0};
    int k = 0;
    for (; k + 4 <= ne; k += 4) {            // 4 independent 16B loads in flight
        float al[4]; bf16x8 hv[4];
#pragma unroll
        for (int u = 0; u < 4; ++u) {
            al[u] = sc[half][k + u][hd] * inv;
            hv[u] = *(const bf16x8*)(hb + (size_t)ssrc[half][k + u] * 1024 + j0);
        }
#pragma unroll
        for (int u = 0; u < 4; ++u)
#pragma unroll
            for (int e = 0; e < 8; ++e)
                a[e] = fmaf(al[u], (float)hv[u][e], a[e]);
    }
    for (; k < ne; ++k) {
        const float al = sc[half][k][hd] * inv;
        const bf16x8 hv = *(const bf16x8*)(hb + (size_t)ssrc[half][k] * 1024 + j0);
#pragma unroll
        for (int e = 0; e < 8; ++e)
            a[e] = fmaf(al, (float)hv[e], a[e]);
    }
    const float4 b4a = *(const float4*)(bias + j0);
    const float4 b4b = *(const float4*)(bias + j0 + 4);
    bf16x8 o;
    o[0] = (__bf16)fmaxf(a[0] + b4a.x, 0.f);
    o[1] = (__bf16)fmaxf(a[1] + b4a.y, 0.f);
    o[2] = (__bf16)fmaxf(a[2] + b4a.z, 0.f);
    o[3] = (__bf16)fmaxf(a[3] + b4a.w, 0.f);
    o[4] = (__bf16)fmaxf(a[4] + b4b.x, 0.f);
    o[5] = (__bf16)fmaxf(a[5] + b4b.y, 0.f);
    o[6] = (__bf16)fmaxf(a[6] + b4b.z, 0.f);
    o[7] = (__bf16)fmaxf(a[7] + b4b.w, 0.f);
    *(bf16x8*)(xout + (size_t)n * 1024 + j0) = o;
}

// ---------------------------------------------------------------------------
// Transpose + fp32->bf16 for W2 and W3 (1024x1024 each), z selects.
__global__ __launch_bounds__(256) void k_transW(
    const float* __restrict__ W2, const float* __restrict__ W3,
    __bf16* __restrict__ W2t, __bf16* __restrict__ W3t)
{
    const float* W = blockIdx.z ? W3 : W2;
    __bf16* WT = blockIdx.z ? W3t : W2t;
    __shared__ float t[32][33];
    const int n0 = blockIdx.x * 32, k0 = blockIdx.y * 32;
    const int tx = threadIdx.x & 31, ty = threadIdx.x >> 5;   // 32 x 8
#pragma unroll
    for (int i = 0; i < 32; i += 8)
        t[ty + i][tx] = W[(size_t)(k0 + ty + i) * 1024 + n0 + tx];
    __syncthreads();
#pragma unroll
    for (int i = 0; i < 32; i += 8)
        WT[(size_t)(n0 + ty + i) * 1024 + k0 + tx] = (__bf16)t[tx][ty + i];
}

// ---------------------------------------------------------------------------
// Transpose Wp/Ws/Wt (1024x256) into WHt[768,1024]; x==8 blocks do biascat.
__global__ __launch_bounds__(256) void k_transH(
    const float* __restrict__ Wp, const float* __restrict__ Ws,
    const float* __restrict__ Wt, __bf16* __restrict__ WHt,
    const float* __restrict__ bp, const float* __restrict__ bs,
    const float* __restrict__ bt, float* __restrict__ bc)
{
    if (blockIdx.x == 8) {
        if (blockIdx.y == 0) {
            const int t = blockIdx.z * 256 + threadIdx.x;
            const float v = blockIdx.z == 0 ? bp[threadIdx.x]
                          : blockIdx.z == 1 ? bs[threadIdx.x] : bt[threadIdx.x];
            bc[t] = v;
        }
        return;
    }
    const float* W = blockIdx.z == 0 ? Wp : blockIdx.z == 1 ? Ws : Wt;
    __bf16* WT = WHt + (size_t)blockIdx.z * 256 * 1024;
    __shared__ float t[32][33];
    const int n0 = blockIdx.x * 32, k0 = blockIdx.y * 32;
    const int tx = threadIdx.x & 31, ty = threadIdx.x >> 5;
#pragma unroll
    for (int i = 0; i < 32; i += 8)
        t[ty + i][tx] = W[(size_t)(k0 + ty + i) * 256 + n0 + tx];
    __syncthreads();
#pragma unroll
    for (int i = 0; i < 32; i += 8)
        WT[(size_t)(n0 + ty + i) * 1024 + k0 + tx] = (__bf16)t[tx][ty + i];
}

// ---------------------------------------------------------------------------
// Best-measured GEMM machinery (R9): 128x128 tile, BK=64, SINGLE 32KB LDS
// buffer. Structural plateau: dbuf (R7), LDS-free (R8), 64-tile/2x-occupancy
// (R10), prep fusion (R11) all measured neutral-or-worse. The per-iter
// vmcnt(0)+barrier drain is not expressible around at HIP source level.
#define STAGE(kbase)                                                           \
    {                                                                          \
        _Pragma("unroll")                                                      \
        for (int h = 0; h < 2; ++h) {                                          \
            _Pragma("unroll")                                                  \
            for (int cc = 0; cc < 2; ++cc) {                                   \
                const int c = 2 * w + cc;                                      \
                const int row = c * 16 + lr;                                   \
                __builtin_amdgcn_global_load_lds(                              \
                    (const __attribute__((address_space(1))) void*)            \
                        (A + (size_t)(m0 + row) * K + (kbase) + h * 32 + lk),  \
                    (__attribute__((address_space(3))) void*)                  \
                        (As + h * 4096 + c * 512), 16, 0, 0);                  \
                __builtin_amdgcn_global_load_lds(                              \
                    (const __attribute__((address_space(1))) void*)            \
                        (BT + (size_t)(n0 + row) * K + (kbase) + h * 32 + lk), \
                    (__attribute__((address_space(3))) void*)                  \
                        (Bs + h * 4096 + c * 512), 16, 0, 0);                  \
            }                                                                  \
        }                                                                      \
    }

#define GEMM_MAINLOOP()                                                        \
    f32x4 acc[4][4];                                                           \
    _Pragma("unroll")                                                          \
    for (int i = 0; i < 4; ++i)                                                \
        _Pragma("unroll")                                                      \
        for (int j = 0; j < 4; ++j)                                            \
            acc[i][j] = (f32x4){0.f, 0.f, 0.f, 0.f};                           \
    for (int k0 = 0; k0 < K; k0 += 64) {                                       \
        STAGE(k0);                                                             \
        __syncthreads();                                                       \
        _Pragma("unroll")                                                      \
        for (int h = 0; h < 2; ++h) {                                          \
            bf16x8 af[4], bfr[4];                                              \
            _Pragma("unroll")                                                  \
            for (int i = 0; i < 4; ++i)                                        \
                af[i] = *(const bf16x8*)(As + h * 4096 +                       \
                                         (wm + i * 16 + r16) * 32 + quad * 8); \
            _Pragma("unroll")                                                  \
            for (int j = 0; j < 4; ++j)                                        \
                bfr[j] = *(const bf16x8*)(Bs + h * 4096 +                      \
                                          (wn + j * 16 + r16) * 32 + quad * 8);\
            _Pragma("unroll")                                                  \
            for (int i = 0; i < 4; ++i)                                        \
                _Pragma("unroll")                                              \
                for (int j = 0; j < 4; ++j)                                    \
                    acc[i][j] = __builtin_amdgcn_mfma_f32_16x16x32_bf16(       \
                        af[i], bfr[j], acc[i][j], 0, 0, 0);                    \
        }                                                                      \
        __syncthreads();                                                       \
    }

// ---------------------------------------------------------------------------
// bf16 MFMA GEMM, h-producing variant: Cb(bf16) = A @ BT^T + fused per-row
// attention dots (fp32 accs, atomics into zeroed asb/adb). N must be 1024.
__global__ __launch_bounds__(256) void gemm_bf16_h(
    const __bf16* __restrict__ A, const __bf16* __restrict__ BT,
    __bf16* __restrict__ Cb,
    const float* __restrict__ atts, const float* __restrict__ attd,
    float* __restrict__ asb, float* __restrict__ adb,
    int M, int N, int K)
{
    const int lb = blockIdx.x;
    const int g = lb & 7, idx = lb >> 3;
    const int bx = idx & 7;                  // nx = 8
    const int by = (idx >> 3) * 8 + g;
    if (by * 128 >= M) return;
    const int m0 = by * 128, n0 = bx * 128;

    __shared__ __bf16 As[2 * 128 * 32];      // 16KB: two 32-k sub-tiles
    __shared__ __bf16 Bs[2 * 128 * 32];      // 16KB
    const int tid = threadIdx.x;
    const int w = tid >> 6, l = tid & 63;
    const int lr = l >> 2, lk = (l & 3) * 8;
    const int quad = l >> 4, r16 = l & 15;
    const int wm = (w >> 1) * 64, wn = (w & 1) * 64;

    GEMM_MAINLOOP();

    // Epilogue: bf16 store + fused attention dots. Hoisted Sa/Da (4 cols/thr).
    const int head = (n0 + wn) >> 8;
    float sa[4], da[4];
#pragma unroll
    for (int j = 0; j < 4; ++j) {
        const int cl = (n0 + wn + j * 16 + r16) & 255;
        sa[j] = atts[head * 256 + cl];
        da[j] = attd[head * 256 + cl];
    }
#pragma unroll
    for (int i = 0; i < 4; ++i) {
#pragma unroll
        for (int r = 0; r < 4; ++r) {
            const int mg = m0 + wm + i * 16 + quad * 4 + r;
            float ps = 0.f, pd = 0.f;
#pragma unroll
            for (int j = 0; j < 4; ++j) {
                const int ng = n0 + wn + j * 16 + r16;
                const float v = acc[i][j][r];
                ps = fmaf(v, sa[j], ps);
                pd = fmaf(v, da[j], pd);
                Cb[(size_t)mg * N + ng] = (__bf16)v;
            }
            for (int off = 8; off; off >>= 1) {
                ps += __shfl_xor(ps, off, 64);
                pd += __shfl_xor(pd, off, 64);
            }
            if (r16 == 0) {
                atomicAdd(&asb[mg * 4 + head], ps);
                atomicAdd(&adb[mg * 4 + head], pd);
            }
        }
    }
}

// ---------------------------------------------------------------------------
// Heads GEMM with fully fused output: relu(acc + biascat) dotted with the
// small head matrices, atomicAdd into zeroed out[]. No T materialization.
__global__ __launch_bounds__(256) void gemm_heads(
    const __bf16* __restrict__ A, const __bf16* __restrict__ BT,
    const float* __restrict__ biascat,
    const float* __restrict__ Wfp, const float* __restrict__ bfp,
    const float* __restrict__ Wfs, const float* __restrict__ bfs,
    const float* __restrict__ Wft, const float* __restrict__ bft,
    float* __restrict__ out, int M, int K)
{
    const int lb = blockIdx.x;
    const int g = lb & 7, idx = lb >> 3;
    const int bx = idx % 6;                  // nx = 6 (N = 768)
    const int by = (idx / 6) * 8 + g;
    if (by * 128 >= M) return;
    const int m0 = by * 128, n0 = bx * 128;

    __shared__ __bf16 As[2 * 128 * 32];
    __shared__ __bf16 Bs[2 * 128 * 32];
    const int tid = threadIdx.x;
    const int w = tid >> 6, l = tid & 63;
    const int lr = l >> 2, lk = (l & 3) * 8;
    const int quad = l >> 4, r16 = l & 15;
    const int wm = (w >> 1) * 64, wn = (w & 1) * 64;

    GEMM_MAINLOOP();

    // Epilogue: per-row partial dots with head weights -> atomics.
    const int hg = bx >> 1;                  // 0 pos, 1 size, 2 theta
    const float* Wf = hg == 0 ? Wfp : hg == 1 ? Wfs : Wft;
    const int nout = hg == 2 ? 1 : 2;
    float wf0[4], wf1[4], bz[4];
#pragma unroll
    for (int j = 0; j < 4; ++j) {
        const int ng = n0 + wn + j * 16 + r16;
        const int cl = ng & 255;
        bz[j]  = biascat[ng];
        wf0[j] = Wf[cl * nout];
        wf1[j] = nout == 2 ? Wf[cl * nout + 1] : 0.f;
    }
    // final bias exactly once per row: even column-block, wn==0 wave only
    const bool addb = ((bx & 1) == 0) && (wn == 0);
    const float fb0 = hg == 0 ? bfp[0] : hg == 1 ? bfs[0] : bft[0];
    const float fb1 = hg == 2 ? 0.f : (hg == 0 ? bfp[1] : bfs[1]);
#pragma unroll
    for (int i = 0; i < 4; ++i) {
#pragma unroll
        for (int r = 0; r < 4; ++r) {
            const int mg = m0 + wm + i * 16 + quad * 4 + r;
            float o0 = 0.f, o1 = 0.f;
#pragma unroll
            for (int j = 0; j < 4; ++j) {
                const float v = fmaxf(acc[i][j][r] + bz[j], 0.f);
                o0 = fmaf(v, wf0[j], o0);
                o1 = fmaf(v, wf1[j], o1);
            }
            for (int off = 8; off; off >>= 1) {
                o0 += __shfl_xor(o0, off, 64);
                o1 += __shfl_xor(o1, off, 64);
            }
            if (r16 == 0) {
                if (addb) { o0 += fb0; o1 += fb1; }
                const size_t base = hg == 0 ? 2 * (size_t)mg
                                 : hg == 1 ? 2 * (size_t)NODES + 2 * (size_t)mg
                                 : 4 * (size_t)NODES + (size_t)mg;
                atomicAdd(&out[base], o0);
                if (nout == 2) atomicAdd(&out[base + 1], o1);
            }
        }
    }
}

// ---------------------------------------------------------------------------
extern "C" void kernel_launch(void* const* d_in, const int* in_sizes, int n_in,
                              void* d_out, int out_size, void* d_ws, size_t ws_size,
                              hipStream_t stream)
{
    const float* z    = (const float*)d_in[0];
    const float* cond = (const float*)d_in[1];
    const int*   ei   = (const int*)  d_in[2];
    const float* Wi   = (const float*)d_in[4];
    const float* bi   = (const float*)d_in[5];
    const float* W1   = (const float*)d_in[6];
    const float* as1  = (const float*)d_in[7];
    const float* ad1  = (const float*)d_in[8];
    const float* b1   = (const float*)d_in[9];
    const float* W2   = (const float*)d_in[10];
    const float* as2  = (const float*)d_in[11];
    const float* ad2  = (const float*)d_in[12];
    const float* b2   = (const float*)d_in[13];
    const float* W3   = (const float*)d_in[14];
    const float* as3  = (const float*)d_in[15];
    const float* ad3  = (const float*)d_in[16];
    const float* b3   = (const float*)d_in[17];
    const float* Wp   = (const float*)d_in[18];
    const float* bp   = (const float*)d_in[19];
    const float* Wfp  = (const float*)d_in[20];
    const float* bfp  = (const float*)d_in[21];
    const float* Ws   = (const float*)d_in[22];
    const float* bs   = (const float*)d_in[23];
    const float* Wfs  = (const float*)d_in[24];
    const float* bfs  = (const float*)d_in[25];
    const float* Wt   = (const float*)d_in[26];
    const float* bt   = (const float*)d_in[27];
    const float* Wft  = (const float*)d_in[28];
    const float* bft  = (const float*)d_in[29];
    float* out = (float*)d_out;

    // ---- workspace carve (bytes) ----
    char* p = (char*)d_ws;
    __bf16* hb    = (__bf16*)p;           p += (size_t)NODES * 1024 * 2;  // 23.6 MB
    __bf16* xb16  = (__bf16*)p;           p += (size_t)NODES * 1024 * 2;  // 23.6 MB
    float* asA    = (float*)p;            p += (size_t)NODES * 4 * 4;
    float* adA    = (float*)p;            p += (size_t)NODES * 4 * 4;
    float* asB    = (float*)p;            p += (size_t)NODES * 4 * 4;
    float* adB    = (float*)p;            p += (size_t)NODES * 4 * 4;
    float* Y1     = (float*)p;            p += 64 * 1024 * 4;
    int*   counts = (int*)p;              p += (size_t)NODES * 4;
    int*   bucket = (int*)p;              p += (size_t)NODES * CAP * 4;   // 2.95 MB
    __bf16* W2t   = (__bf16*)p;           p += (size_t)1024 * 1024 * 2;   // 2 MB
    __bf16* W3t   = (__bf16*)p;           p += (size_t)1024 * 1024 * 2;   // 2 MB
    __bf16* WHt   = (__bf16*)p;           p += (size_t)768 * 1024 * 2;    // 1.5 MB
    float* biascat= (float*)p;            p += 768 * 4;

    hipMemsetAsync(out, 0, (size_t)out_size * sizeof(float), stream);
    hipMemsetAsync(counts, 0, NODES * sizeof(int), stream);

    // ---- weight prep ----
    k_transW<<<dim3(32, 32, 2), 256, 0, stream>>>(W2, W3, W2t, W3t);
    k_transH<<<dim3(9, 32, 3), 256, 0, stream>>>(Wp, Ws, Wt, WHt,
                                                 bp, bs, bt, biascat);
    k_hist<<<EDGES / 256, 256, 0, stream>>>(ei, counts, bucket);

    // ---- layer 1 (GEMM collapsed: one-hot + batch-broadcast structure) ----
    k_init<<<NB, 256, 0, stream>>>(z, cond, Wi, bi, W1, Y1);
    k_h1<<<NODES, 256, 0, stream>>>(Y1, W1, as1, ad1, hb, asA, adA, asB, adB);
    k_agg<<<NODES / 2, 256, 0, stream>>>(hb, asA, adA, counts, bucket, b1,
                                         xb16, nullptr, nullptr);

    // ---- layer 2 (scores fused into GEMM epilogue -> asB/adB) ----
    gemm_bf16_h<<<8 * 96, 256, 0, stream>>>(xb16, W2t, hb, as2, ad2,
                                            asB, adB, NODES, 1024, 1024);
    k_agg<<<NODES / 2, 256, 0, stream>>>(hb, asB, adB, counts, bucket, b2,
                                         xb16, asA, adA);   // zeroes A bufs
    // ---- layer 3 (scores -> asA/adA, zeroed above) ----
    gemm_bf16_h<<<8 * 96, 256, 0, stream>>>(xb16, W3t, hb, as3, ad3,
                                            asA, adA, NODES, 1024, 1024);
    k_agg<<<NODES / 2, 256, 0, stream>>>(hb, asA, adA, counts, bucket, b3,
                                         xb16, nullptr, nullptr);

    // ---- fused heads: dots folded into GEMM epilogue, atomics into out ----
    gemm_heads<<<6 * 96, 256, 0, stream>>>(xb16, WHt, biascat,
                                           Wfp, bfp, Wfs, bfs, Wft, bft,
                                           out, NODES, 1024);
}